// Round 10
// baseline (227.820 us; speedup 1.0000x reference)
//
#include <hip/hip_runtime.h>

#define D_MODEL 1024
#define SEQ_L   2048
#define NHEADS  16
#define HDIM    64
#define NROWS   4096   // B*L

// Q is pre-scaled by (1/sqrt(64)) * log2(e) so softmax uses exp2 directly.
#define QSCALE 0.18033688011112042f
#define LOG2E  1.4426950408889634f

#if __has_builtin(__builtin_amdgcn_exp2f)
#define EXP2F(x) __builtin_amdgcn_exp2f(x)
#else
#define EXP2F(x) __expf((x) * 0.6931471805599453f)
#endif

typedef __attribute__((ext_vector_type(8))) short short8;
typedef __attribute__((ext_vector_type(4))) short short4v;
typedef __attribute__((ext_vector_type(4))) float floatx4;
typedef __attribute__((ext_vector_type(4))) unsigned short ushort4v;
typedef unsigned short ushort;

static __device__ __forceinline__ ushort f2bf(float f) {
    unsigned int u = __float_as_uint(f);
    u += 0x7FFFu + ((u >> 16) & 1u);
    return (ushort)(u >> 16);
}

static __device__ __forceinline__ floatx4 mfma16(short8 a, short8 b, floatx4 c) {
    return __builtin_amdgcn_mfma_f32_16x16x32_bf16(a, b, c, 0, 0, 0);
}

static __device__ __forceinline__ floatx4 mfma16k16(short4v a, short4v b, floatx4 c) {
    return __builtin_amdgcn_mfma_f32_16x16x16bf16_1k(a, b, c, 0, 0, 0);
}

static __device__ __forceinline__ void store8bf(ushort* dst, float4 a, float4 b) {
    uint4 pk;
    pk.x = (unsigned)f2bf(a.x) | ((unsigned)f2bf(a.y) << 16);
    pk.y = (unsigned)f2bf(a.z) | ((unsigned)f2bf(a.w) << 16);
    pk.z = (unsigned)f2bf(b.x) | ((unsigned)f2bf(b.y) << 16);
    pk.w = (unsigned)f2bf(b.z) | ((unsigned)f2bf(b.w) << 16);
    *(uint4*)dst = pk;
}

// async global->LDS, 16B per lane.
static __device__ __forceinline__ void gll16(const ushort* g, ushort* l) {
    __builtin_amdgcn_global_load_lds(
        (const __attribute__((address_space(1))) unsigned int*)(const unsigned int*)g,
        (__attribute__((address_space(3))) unsigned int*)(unsigned int*)l,
        16, 0, 0);
}

// ---------------------------------------------------------------------------
// Kernel 0: fp32 -> bf16, WEIGHTS ONLY (x is converted inside gemm_qkv).
// Flat grid, no dead blocks: 4 segments x 1M elements.
// ---------------------------------------------------------------------------
__global__ __launch_bounds__(256) void convert_w(
    const float* __restrict__ wq, const float* __restrict__ wk,
    const float* __restrict__ wv, const float* __restrict__ wo,
    ushort* __restrict__ wb3, ushort* __restrict__ wob)
{
    const int i = (blockIdx.x * 256 + threadIdx.x) * 8;   // 0 .. 4M-8
    const int seg = i >> 20;
    const int within = i & 1048575;
    const float* src = (seg == 0) ? wq : (seg == 1) ? wk : (seg == 2) ? wv : wo;
    ushort* dst = (seg < 3) ? (wb3 + i) : (wob + within);
    float4 a = *(const float4*)(src + within);
    float4 b = *(const float4*)(src + within + 4);
    store8bf(dst, a, b);
}

// ---------------------------------------------------------------------------
// Kernel 1: fused QKV GEMM. 64(M)x128(N)xBK64, grid 24x64 = 1536 blocks.
// A staged from x FP32 directly (register load -> f2bf -> ds_write_b128);
// B staged async via global_load_lds from bf16 weights.
// Q/K use SWAPPED operand order (C^T) -> ushort4 epilogue stores.
// ---------------------------------------------------------------------------
__global__ __launch_bounds__(256, 4) void gemm_qkv(
    const float* __restrict__ X, const ushort* __restrict__ B,
    const float* __restrict__ bq, const float* __restrict__ bk,
    const float* __restrict__ bv,
    ushort* __restrict__ Qo, ushort* __restrict__ Ko, ushort* __restrict__ Vo)
{
    __shared__ ushort As[64 * 64];    //  8 KB
    __shared__ ushort Bs[128 * 64];   // 16 KB

    const int tid  = threadIdx.x;
    const int w    = tid >> 6;
    const int lane = tid & 63;
    const int l15  = lane & 15;
    const int quad = lane >> 4;

    const int bm = blockIdx.y * 64;     // x-row tile
    const int bn = blockIdx.x * 128;    // weight-col tile (0..3071)
    const int z  = blockIdx.x >> 3;     // 0=Q, 1=K, 2=V

    // --- A staging (fp32 source): chunk ci -> row=ci>>3, slot=ci&7,
    //     global chunk g = slot^(row&7); 8 fp32 per chunk.
    const int ciA0 = tid, ciA1 = tid + 256;
    const int rA0 = ciA0 >> 3, rA1 = ciA1 >> 3;
    const int sA0 = ciA0 & 7,  sA1 = ciA1 & 7;
    const float* axP0 = X + (size_t)(bm + rA0) * 1024 + (sA0 ^ (rA0 & 7)) * 8;
    const float* axP1 = X + (size_t)(bm + rA1) * 1024 + (sA1 ^ (rA1 & 7)) * 8;
    ushort* lA0 = &As[rA0 * 64 + sA0 * 8];
    ushort* lA1 = &As[rA1 * 64 + sA1 * 8];

    // --- B staging (bf16, async): 1024 chunks
    const ushort* bP[4];
    ushort* lB[4];
#pragma unroll
    for (int p = 0; p < 4; p++) {
        const int ci = tid + p * 256;
        const int r = ci >> 3, s = ci & 7;
        bP[p] = B + (size_t)(bn + r) * 1024 + (s ^ (r & 7)) * 8;
        lB[p] = &Bs[r * 64 + s * 8];
    }

    const int x7 = l15 & 7;

    floatx4 acc[4][2];
#pragma unroll
    for (int i = 0; i < 4; i++)
#pragma unroll
        for (int j = 0; j < 2; j++) acc[i][j] = (floatx4){0.f, 0.f, 0.f, 0.f};

    for (int k0 = 0; k0 < 1024; k0 += 64) {
        __syncthreads();
#pragma unroll
        for (int p = 0; p < 4; p++) gll16(bP[p] + k0, lB[p]);
        float4 fa00 = *(const float4*)(axP0 + k0);
        float4 fa01 = *(const float4*)(axP0 + k0 + 4);
        float4 fa10 = *(const float4*)(axP1 + k0);
        float4 fa11 = *(const float4*)(axP1 + k0 + 4);
        store8bf(lA0, fa00, fa01);
        store8bf(lA1, fa10, fa11);
        __syncthreads();

#pragma unroll
        for (int kk = 0; kk < 2; kk++) {
            const int slot = ((kk * 4 + quad) ^ x7) * 8;
            short8 af[4], bf[2];
#pragma unroll
            for (int mi = 0; mi < 4; mi++)
                af[mi] = *(const short8*)&As[(mi * 16 + l15) * 64 + slot];
#pragma unroll
            for (int ni = 0; ni < 2; ni++)
                bf[ni] = *(const short8*)&Bs[(w * 32 + ni * 16 + l15) * 64 + slot];
            if (z == 2) {
#pragma unroll
                for (int mi = 0; mi < 4; mi++)
#pragma unroll
                    for (int ni = 0; ni < 2; ni++)
                        acc[mi][ni] = mfma16(af[mi], bf[ni], acc[mi][ni]);
            } else {
#pragma unroll
                for (int mi = 0; mi < 4; mi++)
#pragma unroll
                    for (int ni = 0; ni < 2; ni++)
                        acc[mi][ni] = mfma16(bf[ni], af[mi], acc[mi][ni]);
            }
        }
    }

    const int cwbase = bn & 1023;
    if (z == 2) {
        // ----- V epilogue (normal): lane col = l15, rows quad*4+r -> V^T store
#pragma unroll
        for (int ni = 0; ni < 2; ni++) {
            const int within = cwbase + w * 32 + ni * 16 + l15;
            const int h  = within >> 6;
            const int hd = within & 63;
            const float bvl = bv[within];
#pragma unroll
            for (int mi = 0; mi < 4; mi++) {
                const int row = bm + mi * 16 + quad * 4;
                const int bb = row >> 11, li = row & 2047;
                ushort4v pk;
#pragma unroll
                for (int r = 0; r < 4; r++) pk[r] = f2bf(acc[mi][ni][r] + bvl);
                *(ushort4v*)(Vo + ((size_t)(bb * NHEADS + h) * HDIM + hd) * SEQ_L + li) = pk;
            }
        }
    } else {
        // ----- Q/K epilogue (C^T): lane holds 4 consecutive weight cols -----
        const float* bias = z ? bk : bq;
        const float scale = z ? 1.0f : QSCALE;
        ushort* outp = z ? Ko : Qo;
#pragma unroll
        for (int ni = 0; ni < 2; ni++) {
            const int colw = cwbase + w * 32 + ni * 16 + quad * 4;
            const int h   = colw >> 6;
            const int hd0 = colw & 63;
            const float4 bb4 = *(const float4*)&bias[colw];
#pragma unroll
            for (int mi = 0; mi < 4; mi++) {
                const int row = bm + mi * 16 + l15;
                const int bb = row >> 11, li = row & 2047;
                ushort4v pk;
                pk[0] = f2bf((acc[mi][ni][0] + bb4.x) * scale);
                pk[1] = f2bf((acc[mi][ni][1] + bb4.y) * scale);
                pk[2] = f2bf((acc[mi][ni][2] + bb4.z) * scale);
                pk[3] = f2bf((acc[mi][ni][3] + bb4.w) * scale);
                *(ushort4v*)(outp + ((size_t)(bb * NHEADS + h) * SEQ_L + li) * HDIM + hd0) = pk;
            }
        }
    }
}

// ---------------------------------------------------------------------------
// Kernel 2: flash attention, S^T formulation, 128-query blocks, 2-way K-split.
// (unchanged from R9)
// ---------------------------------------------------------------------------
__global__ __launch_bounds__(256, 4) void attn(
    const ushort* __restrict__ Q,
    const ushort* __restrict__ K,
    const ushort* __restrict__ Vt,
    const float* __restrict__ lam,
    ushort* __restrict__ O0, ushort* __restrict__ O1,
    float* __restrict__ Lw)
{
    __shared__ float mtab[128];
    __shared__ ushort Ks[2][64 * 64];
    __shared__ ushort Vts[2][64 * 64];

    const int tid  = threadIdx.x;
    const int wave = tid >> 6;
    const int lane = tid & 63;
    const int l15  = lane & 15;
    const int quad = lane >> 4;

    const int qb = blockIdx.x;           // 0..15
    const int h  = blockIdx.y;
    const int zz = blockIdx.z;           // 0..3
    const int bz = zz >> 1;
    const int sp = zz & 1;               // key split
    const int bh = bz * NHEADS + h;
    const int q0 = qb * 128;
    const int kb = sp * 1024;            // key base

    const float lambda = *lam;
    if (tid < 128) {
        float d  = (float)tid;
        float e1 = (d - 1.f) * (d - 1.f);
        float e2 = (d - 30.f) * (d - 30.f);
        mtab[tid] = LOG2E * lambda *
                    (0.8f * __expf(-2.0f * e1) + 0.4f * __expf(-0.125f * e2));
    }

    const ushort* qp =
        Q + ((size_t)bh * SEQ_L + q0 + wave * 16 + l15) * HDIM + quad * 8;
    short8 qf[2][2];
    qf[0][0] = *(const short8*)qp;
    qf[0][1] = *(const short8*)(qp + 32);
    qf[1][0] = *(const short8*)(qp + 64 * HDIM);
    qf[1][1] = *(const short8*)(qp + 64 * HDIM + 32);

    const ushort* kbase = K  + ((size_t)bh * SEQ_L) * HDIM;
    const ushort* vbase = Vt + ((size_t)bh * HDIM) * SEQ_L;

    const int cid0 = tid, cid1 = 256 + tid;
    const int row0 = cid0 >> 3, row1 = cid1 >> 3;
    const int cl0  = (cid0 & 7) ^ (row0 & 7);
    const int cl1  = (cid1 & 7) ^ (row1 & 7);
    const ushort* kg0 = kbase + (size_t)(kb + row0) * HDIM + cl0 * 8;
    const ushort* kg1 = kbase + (size_t)(kb + row1) * HDIM + cl1 * 8;
    const ushort* vg0 = vbase + (size_t)row0 * SEQ_L + kb + cl0 * 8;
    const ushort* vg1 = vbase + (size_t)row1 * SEQ_L + kb + cl1 * 8;

    floatx4 o[2][4];
#pragma unroll
    for (int g = 0; g < 2; g++)
#pragma unroll
        for (int i = 0; i < 4; i++) o[g][i] = (floatx4){0.f, 0.f, 0.f, 0.f};
    floatx4 ol[2];
    ol[0] = (floatx4){0.f, 0.f, 0.f, 0.f};
    ol[1] = (floatx4){0.f, 0.f, 0.f, 0.f};

    short4v ones;
    ones[0] = 0x3F80; ones[1] = 0x3F80; ones[2] = 0x3F80; ones[3] = 0x3F80;

    gll16(kg0, &Ks[0][cid0 * 8]);
    gll16(kg1, &Ks[0][cid1 * 8]);
    gll16(vg0, &Vts[0][cid0 * 8]);
    gll16(vg1, &Vts[0][cid1 * 8]);

    const int xo = l15 & 7;

    for (int t = 0; t < 16; t++) {
        const int cur = t & 1;
        __syncthreads();
        if (t + 1 < 16) {
            const int nxt = cur ^ 1;
            const int koff = (t + 1) * 64;
            gll16(kg0 + (size_t)koff * HDIM, &Ks[nxt][cid0 * 8]);
            gll16(kg1 + (size_t)koff * HDIM, &Ks[nxt][cid1 * 8]);
            gll16(vg0 + koff, &Vts[nxt][cid0 * 8]);
            gll16(vg1 + koff, &Vts[nxt][cid1 * 8]);
        }

        floatx4 s[2][4];
#pragma unroll
        for (int g = 0; g < 2; g++)
#pragma unroll
            for (int i = 0; i < 4; i++) s[g][i] = (floatx4){0.f, 0.f, 0.f, 0.f};
#pragma unroll
        for (int kk = 0; kk < 2; kk++) {
#pragma unroll
            for (int nt = 0; nt < 4; nt++) {
                const int slot = (kk * 4 + quad) ^ xo;
                short8 kf = *(const short8*)&Ks[cur][(nt * 16 + l15) * 64 + slot * 8];
                s[0][nt] = mfma16(kf, qf[0][kk], s[0][nt]);
                s[1][nt] = mfma16(kf, qf[1][kk], s[1][nt]);
            }
        }

        const int j = sp * 16 + t;   // global key tile index
#pragma unroll
        for (int g = 0; g < 2; g++) {
            const int tg = j - (qb * 2 + g);
            if (tg >= -1 && tg <= 1) {
                const int qg = q0 + g * 64 + wave * 16 + l15;
#pragma unroll
                for (int nt = 0; nt < 4; nt++) {
                    const int kgi = j * 64 + nt * 16 + quad * 4;
#pragma unroll
                    for (int r = 0; r < 4; r++) {
                        int dq = qg - (kgi + r);
                        int ad = dq < 0 ? -dq : dq;
                        s[g][nt][r] += mtab[ad];
                    }
                }
            }
        }

        short4v pb[2][4];
#pragma unroll
        for (int g = 0; g < 2; g++) {
#pragma unroll
            for (int nt = 0; nt < 4; nt++) {
                unsigned ur[4];
#pragma unroll
                for (int r = 0; r < 4; r++)
                    ur[r] = __float_as_uint(EXP2F(s[g][nt][r])) + 0x8000u;
                uint2 pk;
                pk.x = __builtin_amdgcn_perm(ur[1], ur[0], 0x07060302u);
                pk.y = __builtin_amdgcn_perm(ur[3], ur[2], 0x07060302u);
                pb[g][nt] = __builtin_bit_cast(short4v, pk);
            }
        }

#pragma unroll
        for (int kc = 0; kc < 4; kc++) {
#pragma unroll
            for (int nt = 0; nt < 4; nt++) {
                const int slot = (2 * kc + (quad >> 1)) ^ xo;
                short4v vf = *(const short4v*)
                    &Vts[cur][(nt * 16 + l15) * 64 + slot * 8 + (quad & 1) * 4];
                o[0][nt] = mfma16k16(vf, pb[0][kc], o[0][nt]);
                o[1][nt] = mfma16k16(vf, pb[1][kc], o[1][nt]);
            }
            ol[0] = mfma16k16(ones, pb[0][kc], ol[0]);
            ol[1] = mfma16k16(ones, pb[1][kc], ol[1]);
        }
    }

    ushort* Osp = sp ? O1 : O0;
#pragma unroll
    for (int g = 0; g < 2; g++) {
        const int qg = q0 + g * 64 + wave * 16 + l15;
        if (quad == 0)
            Lw[((size_t)(sp * 2 + bz) * NHEADS + h) * SEQ_L + qg] = ol[g][0];
        ushort* obase = Osp + ((size_t)bz * SEQ_L + qg) * D_MODEL + h * HDIM;
#pragma unroll
        for (int nt = 0; nt < 4; nt++) {
            ushort4v pk;
#pragma unroll
            for (int r = 0; r < 4; r++) pk[r] = f2bf(o[g][nt][r]);
            *(ushort4v*)(obase + nt * 16 + quad * 4) = pk;
        }
    }
}

// ---------------------------------------------------------------------------
// Kernel 3: output projection WITH FUSED MERGE. A = (O0+O1) * rcp(L0+L1),
// computed in-register during A staging (BK=64 window = exactly one head).
// 64x64xBK64 tiles, grid 16x64, SWAPPED operands -> C^T -> float4 stores.
// ---------------------------------------------------------------------------
__global__ __launch_bounds__(256, 4) void gemm_out(
    const ushort* __restrict__ O0, const ushort* __restrict__ O1,
    const float* __restrict__ Lw,
    const ushort* __restrict__ B,
    const float* __restrict__ bo, float* __restrict__ out)
{
    __shared__ ushort As[64 * 64];   // 8 KB
    __shared__ ushort Bs[64 * 64];   // 8 KB

    const int tid  = threadIdx.x;
    const int w    = tid >> 6;
    const int lane = tid & 63;
    const int l15  = lane & 15;
    const int quad = lane >> 4;

    const int bm = blockIdx.y * 64;
    const int bn = blockIdx.x * 64;
    const int bz = bm >> 11;                 // uniform: 64 | 2048
    const int NL = 2 * NHEADS * SEQ_L;       // split-1 L offset

    const int ci0 = tid, ci1 = tid + 256;    // 512 chunks per tile
    const int r0 = ci0 >> 3, r1 = ci1 >> 3;
    const int s0 = ci0 & 7,  s1 = ci1 & 7;
    const int c0 = (s0 ^ (r0 & 7)) * 8;      // global col offset within k-window
    const int c1 = (s1 ^ (r1 & 7)) * 8;
    const ushort* o0P0 = O0 + (size_t)(bm + r0) * 1024 + c0;
    const ushort* o0P1 = O0 + (size_t)(bm + r1) * 1024 + c1;
    const ushort* o1P0 = O1 + (size_t)(bm + r0) * 1024 + c0;
    const ushort* o1P1 = O1 + (size_t)(bm + r1) * 1024 + c1;
    const int liB0 = bz * NHEADS * SEQ_L + ((bm + r0) & 2047);
    const int liB1 = bz * NHEADS * SEQ_L + ((bm + r1) & 2047);
    const ushort* bP0 = B + (size_t)(bn + r0) * 1024 + c0;
    const ushort* bP1 = B + (size_t)(bn + r1) * 1024 + c1;
    ushort* lA0 = &As[r0 * 64 + s0 * 8];
    ushort* lA1 = &As[r1 * 64 + s1 * 8];
    ushort* lB0 = &Bs[r0 * 64 + s0 * 8];
    ushort* lB1 = &Bs[r1 * 64 + s1 * 8];

    const int x7 = l15 & 7;

    floatx4 acc[4];
#pragma unroll
    for (int i = 0; i < 4; i++) acc[i] = (floatx4){0.f, 0.f, 0.f, 0.f};

    for (int k0 = 0; k0 < 1024; k0 += 64) {
        __syncthreads();
        gll16(bP0 + k0, lB0);
        gll16(bP1 + k0, lB1);

        const int hoff = (k0 >> 6) * SEQ_L;
        const float linv0 = __builtin_amdgcn_rcpf(
            Lw[liB0 + hoff] + Lw[NL + liB0 + hoff]);
        const float linv1 = __builtin_amdgcn_rcpf(
            Lw[liB1 + hoff] + Lw[NL + liB1 + hoff]);

        uint4 a0 = *(const uint4*)(o0P0 + k0);
        uint4 b0 = *(const uint4*)(o1P0 + k0);
        uint4 a1 = *(const uint4*)(o0P1 + k0);
        uint4 b1 = *(const uint4*)(o1P1 + k0);

        uint4 res0, res1;
        {
            unsigned aw[4] = {a0.x, a0.y, a0.z, a0.w};
            unsigned bw[4] = {b0.x, b0.y, b0.z, b0.w};
            unsigned rw[4];
#pragma unroll
            for (int k = 0; k < 4; k++) {
                float lo = (__uint_as_float(aw[k] << 16) +
                            __uint_as_float(bw[k] << 16)) * linv0;
                float hi = (__uint_as_float(aw[k] & 0xFFFF0000u) +
                            __uint_as_float(bw[k] & 0xFFFF0000u)) * linv0;
                rw[k] = ((__float_as_uint(lo) + 0x8000u) >> 16) |
                        ((__float_as_uint(hi) + 0x8000u) & 0xFFFF0000u);
            }
            res0.x = rw[0]; res0.y = rw[1]; res0.z = rw[2]; res0.w = rw[3];
        }
        {
            unsigned aw[4] = {a1.x, a1.y, a1.z, a1.w};
            unsigned bw[4] = {b1.x, b1.y, b1.z, b1.w};
            unsigned rw[4];
#pragma unroll
            for (int k = 0; k < 4; k++) {
                float lo = (__uint_as_float(aw[k] << 16) +
                            __uint_as_float(bw[k] << 16)) * linv1;
                float hi = (__uint_as_float(aw[k] & 0xFFFF0000u) +
                            __uint_as_float(bw[k] & 0xFFFF0000u)) * linv1;
                rw[k] = ((__float_as_uint(lo) + 0x8000u) >> 16) |
                        ((__float_as_uint(hi) + 0x8000u) & 0xFFFF0000u);
            }
            res1.x = rw[0]; res1.y = rw[1]; res1.z = rw[2]; res1.w = rw[3];
        }
        *(uint4*)lA0 = res0;
        *(uint4*)lA1 = res1;
        __syncthreads();

#pragma unroll
        for (int kk = 0; kk < 2; kk++) {
            const int slot = ((kk * 4 + quad) ^ x7) * 8;
            short8 bf = *(const short8*)&Bs[(w * 16 + l15) * 64 + slot];
#pragma unroll
            for (int mi = 0; mi < 4; mi++) {
                short8 af = *(const short8*)&As[(mi * 16 + l15) * 64 + slot];
                acc[mi] = mfma16(bf, af, acc[mi]);
            }
        }
    }

    // D^T: lane holds x-row = l15, out-col = w*16 + quad*4 + r (consecutive)
    const int col0 = bn + w * 16 + quad * 4;
    const float4 bb4 = *(const float4*)&bo[col0];
#pragma unroll
    for (int mi = 0; mi < 4; mi++) {
        const int row = bm + mi * 16 + l15;
        float4 st;
        st.x = acc[mi][0] + bb4.x;
        st.y = acc[mi][1] + bb4.y;
        st.z = acc[mi][2] + bb4.z;
        st.w = acc[mi][3] + bb4.w;
        *(float4*)(out + (size_t)row * 1024 + col0) = st;
    }
}

// ---------------------------------------------------------------------------
extern "C" void kernel_launch(void* const* d_in, const int* in_sizes, int n_in,
                              void* d_out, int out_size, void* d_ws, size_t ws_size,
                              hipStream_t stream)
{
    const float* x   = (const float*)d_in[0];
    const float* Wq  = (const float*)d_in[1];
    const float* bq  = (const float*)d_in[2];
    const float* Wk  = (const float*)d_in[3];
    const float* bk  = (const float*)d_in[4];
    const float* Wv  = (const float*)d_in[5];
    const float* bv  = (const float*)d_in[6];
    const float* Wo  = (const float*)d_in[7];
    const float* bo  = (const float*)d_in[8];
    const float* lam = (const float*)d_in[9];
    float* out = (float*)d_out;

    const size_t NELEM = (size_t)NROWS * D_MODEL;   // 4194304
    ushort* Qw  = (ushort*)d_ws;                    //  8 MB
    ushort* Kw  = Qw + NELEM;                       //  8 MB
    ushort* Vw  = Kw + NELEM;                       //  8 MB
    ushort* O0  = Vw + NELEM;                       //  8 MB
    ushort* O1  = O0 + NELEM;                       //  8 MB
    ushort* Wb3 = O1 + NELEM;                       //  6 MB
    ushort* Wob = Wb3 + 3 * 1024 * 1024;            //  2 MB
    float*  Lw  = (float*)(Wob + 1024 * 1024);      //  512 KB

    convert_w<<<2048, 256, 0, stream>>>(Wq, Wk, Wv, Wo, Wb3, Wob);

    dim3 g1(3072 / 128, NROWS / 64);   // 24 x 64 = 1536 blocks
    gemm_qkv<<<g1, 256, 0, stream>>>(x, Wb3, bq, bk, bv, Qw, Kw, Vw);

    dim3 g2(SEQ_L / 128, NHEADS, 4);   // z = batch*2 + key-split
    attn<<<g2, 256, 0, stream>>>(Qw, Kw, Vw, lam, O0, O1, Lw);

    dim3 g3(1024 / 64, NROWS / 64);    // 16 x 64 = 1024 blocks
    gemm_out<<<g3, 256, 0, stream>>>(O0, O1, Lw, Wob, bo, out);
}